// Round 1
// baseline (370.668 us; speedup 1.0000x reference)
//
#include <hip/hip_runtime.h>
#include <cfloat>
#include <cstdint>

#define NN 8192      // nodes
#define DD 128       // features
#define WPR 256      // bitmask words per row (8192/32)
#define TOPK 32

// monotonic float -> uint mapping (descending float == descending uint)
__device__ __forceinline__ uint32_t f2s(float f) {
  uint32_t u = __float_as_uint(f);
  return (u & 0x80000000u) ? ~u : (u | 0x80000000u);
}
__device__ __forceinline__ float s2f(uint32_t s) {
  return (s & 0x80000000u) ? __uint_as_float(s & 0x7fffffffu)
                           : __uint_as_float(~s);
}
__device__ __forceinline__ unsigned long long shfl_down_u64(unsigned long long v, int off) {
  unsigned lo = __shfl_down((unsigned)(v & 0xffffffffull), off, 64);
  unsigned hi = __shfl_down((unsigned)(v >> 32), off, 64);
  return ((unsigned long long)hi << 32) | (unsigned long long)lo;
}

// Fused prep kernel:
//   blocks [0, DD)        : exact top-32 (value, index) per feature column, descending
//   blocks [DD, DD+NN)    : adj row -> 256-word bitmask + has_nbr flag (streams all of adj)
__global__ __launch_bounds__(256) void prep_kernel(
    const float* __restrict__ x, const int* __restrict__ adj,
    uint32_t* __restrict__ bits, int* __restrict__ has_nbr,
    float* __restrict__ tkv, int* __restrict__ tki) {
  const int b = blockIdx.x;
  const int t = threadIdx.x;

  __shared__ unsigned long long red[4];
  __shared__ unsigned long long bcast;
  __shared__ int anyflag;

  if (b >= DD) {
    // ---- bitmask build for one adjacency row ----
    const int row = b - DD;
    const uint4* src = ((const uint4*)(adj + (size_t)row * NN)) + (size_t)t * 8;
    uint32_t w = 0;
#pragma unroll
    for (int c = 0; c < 8; ++c) {
      uint4 v = src[c];                       // ints [32t+4c .. 32t+4c+3]
      w |= (v.x ? 1u : 0u) << (4 * c + 0);
      w |= (v.y ? 1u : 0u) << (4 * c + 1);
      w |= (v.z ? 1u : 0u) << (4 * c + 2);
      w |= (v.w ? 1u : 0u) << (4 * c + 3);
    }
    bits[(size_t)row * WPR + t] = w;
    if (t == 0) anyflag = 0;
    __syncthreads();
    if (w) anyflag = 1;                       // benign same-value race
    __syncthreads();
    if (t == 0) has_nbr[row] = anyflag;
  } else {
    // ---- exact top-32 of column x[:, d], descending ----
    const int d = b;
    float vals[32];
#pragma unroll
    for (int e = 0; e < 32; ++e) {
      int j = t * 32 + e;
      vals[e] = x[(size_t)j * DD + d];
    }
    unsigned long long prev = ~0ull;          // keys strictly below prev each round
    for (int k = 0; k < TOPK; ++k) {
      unsigned long long best = 0ull;
#pragma unroll
      for (int e = 0; e < 32; ++e) {
        int j = t * 32 + e;
        unsigned long long key =
            ((unsigned long long)f2s(vals[e]) << 32) | (unsigned)j;
        if (key < prev && key > best) best = key;
      }
      // wave reduce (64 lanes)
      for (int off = 32; off; off >>= 1) {
        unsigned long long o = shfl_down_u64(best, off);
        if (o > best) best = o;
      }
      const int lane = t & 63, wv = t >> 6;
      if (lane == 0) red[wv] = best;
      __syncthreads();
      if (t == 0) {
        unsigned long long m = red[0];
        for (int i = 1; i < 4; ++i) if (red[i] > m) m = red[i];
        bcast = m;
        uint32_t s = (uint32_t)(m >> 32);
        uint32_t j = (uint32_t)(m & 0xffffffffu);
        tkv[k * DD + d] = s2f(s);
        tki[k * DD + d] = (int)j;
      }
      __syncthreads();
      prev = bcast;
    }
  }
}

// Probe kernel: 2 rows per block; wave = 64 features of one row.
__global__ __launch_bounds__(256) void probe_kernel(
    const float* __restrict__ x, const uint32_t* __restrict__ bits,
    const int* __restrict__ has_nbr, const float* __restrict__ tkv,
    const int* __restrict__ tki, float* __restrict__ out) {
  const int t = threadIdx.x;
  const int row = blockIdx.x * 2 + (t >> 7);
  const int d = t & 127;
  const uint32_t* rb = bits + (size_t)row * WPR;

  float res = 0.0f;
  bool done = false;
  for (int k = 0; k < TOPK; ++k) {
    int idx = tki[k * DD + d];
    float val = tkv[k * DD + d];
    uint32_t w = rb[idx >> 5];
    bool hit = (w >> (idx & 31)) & 1u;
    if (!done && hit) { res = val; done = true; }
    if (__all((int)done)) break;              // wave-uniform early exit
  }
  if (__any((int)(!done))) {
    // rare (~2^-32 per element): neighbors exist but none in top-32 -> full scan
    if (!done && has_nbr[row]) {
      float m = -FLT_MAX;
      for (int wd = 0; wd < WPR; ++wd) {
        uint32_t bm = rb[wd];
        while (bm) {
          int j = wd * 32 + __ffs(bm) - 1;
          bm &= bm - 1;
          m = fmaxf(m, x[(size_t)j * DD + d]);
        }
      }
      res = m;
    }
    // !done && !has_nbr -> res stays 0 (matches reference)
  }
  out[(size_t)row * DD + d] = res;
}

extern "C" void kernel_launch(void* const* d_in, const int* in_sizes, int n_in,
                              void* d_out, int out_size, void* d_ws, size_t ws_size,
                              hipStream_t stream) {
  const float* x = (const float*)d_in[0];   // [8192,128] f32
  const int* adj = (const int*)d_in[1];     // [8192,8192] i32
  float* out = (float*)d_out;               // [8192,128] f32

  // workspace layout (8.06 MB total)
  uint32_t* bits = (uint32_t*)d_ws;                                   // 8 MB
  int* has_nbr = (int*)((char*)d_ws + (size_t)NN * WPR * 4);          // 32 KB
  float* tkv = (float*)((char*)has_nbr + (size_t)NN * 4);             // 16 KB
  int* tki = (int*)((char*)tkv + (size_t)TOPK * DD * 4);              // 16 KB

  prep_kernel<<<NN + DD, 256, 0, stream>>>(x, adj, bits, has_nbr, tkv, tki);
  probe_kernel<<<NN / 2, 256, 0, stream>>>(x, bits, has_nbr, tkv, tki, out);
}